// Round 2
// baseline (318.651 us; speedup 1.0000x reference)
//
#include <hip/hip_runtime.h>

#define IN_CH   128
#define OUT_CH  64
#define M_TILE  128         // nodes per block in the MFMA GEMM
#define XS_PITCH 136        // 128 bf16 + 8 pad (272 B row) -> conflict-free frags

#define NB         64       // nodes per prop block (target range)
#define ACC_STRIDE 68       // f32 words per LDS acc row (64 + 4 pad -> flush banks spread)

typedef __attribute__((ext_vector_type(8))) short short8;
typedef __attribute__((ext_vector_type(4))) float floatx4;

__device__ __forceinline__ unsigned short f2bf(float f) {
    union { float f; unsigned u; } v; v.f = f;
    unsigned r = v.u + 0x7fffu + ((v.u >> 16) & 1u);   // RNE
    return (unsigned short)(r >> 16);
}
__device__ __forceinline__ float bfl(unsigned u) {   // low bf16 -> f32
    return __uint_as_float(u << 16);
}
__device__ __forceinline__ float bfh(unsigned u) {   // high bf16 -> f32
    return __uint_as_float(u & 0xffff0000u);
}

// ---------------------------------------------------------------------------
// Kernel 1 (prep): CSR row pointers (lower_bound over sorted targets) for both
// edge sets, PLUS bf16 pre-pack of the combined transposed weights
// WcT[n][k] = bf16(Wc[k][n]), Wc = [Wmi+Ws | Wmo+Ws]  (128x128).
// ---------------------------------------------------------------------------
__global__ void prep_kernel(const int* __restrict__ tgtIn,
                            const int* __restrict__ tgtOut,
                            const float* __restrict__ Wmi,
                            const float* __restrict__ Wmo,
                            const float* __restrict__ Wsh,
                            int* __restrict__ rpIn,
                            int* __restrict__ rpOut,
                            unsigned short* __restrict__ WcT,
                            int n_nodes, int neIn, int neOut)
{
    int i = blockIdx.x * blockDim.x + threadIdx.x;
    int half = n_nodes + 1;
    if (i < 2 * half) {
        const int* tgt; int* rp; int t; int ne;
        if (i < half) { tgt = tgtIn;  rp = rpIn;  t = i;        ne = neIn; }
        else          { tgt = tgtOut; rp = rpOut; t = i - half; ne = neOut; }
        int lo = 0, hi = ne;
        while (lo < hi) {
            int mid = (lo + hi) >> 1;
            if (tgt[mid] < t) lo = mid + 1; else hi = mid;
        }
        rp[t] = lo;
    } else {
        int j = i - 2 * half;
        if (j < 2 * OUT_CH * IN_CH) {
            int n = j >> 7, k = j & 127;     // n: output col of Wc, k: input ch
            float m = (n < OUT_CH) ? Wmi[k * OUT_CH + n]
                                   : Wmo[k * OUT_CH + (n - OUT_CH)];
            float s = Wsh[k * OUT_CH + (n & (OUT_CH - 1))];
            WcT[n * IN_CH + k] = f2bf(m + s);
        }
    }
}

// ---------------------------------------------------------------------------
// Kernel 2 (MFMA GEMM): H = x_bf16 @ WcT^T. Unchanged from R1.
// ---------------------------------------------------------------------------
__global__ __launch_bounds__(256, 3)
void gemm_kernel(const float* __restrict__ x,
                 const unsigned short* __restrict__ WcT,
                 unsigned short* __restrict__ Abf,
                 unsigned short* __restrict__ Bbf,
                 int n_nodes)
{
    __shared__ unsigned short Xs[M_TILE][XS_PITCH];   // 34.8 KB

    const int tid  = threadIdx.x;
    const int w    = tid >> 6;
    const int lane = tid & 63;
    const int l15  = lane & 15;
    const int quad = lane >> 4;
    const long long node0 = (long long)blockIdx.x * M_TILE;

    short8 bfrag[4][2];
#pragma unroll
    for (int ks = 0; ks < 4; ++ks)
#pragma unroll
        for (int ni = 0; ni < 2; ++ni)
            bfrag[ks][ni] = *(const short8*)&WcT[(w * 32 + ni * 16 + l15) * IN_CH
                                                 + ks * 32 + quad * 8];

    {
        const float4* x4 = (const float4*)x;
        for (int i = tid; i < M_TILE * (IN_CH / 4); i += 256) {
            int row = i >> 5, c4 = i & 31;
            long long node = node0 + row;
            float4 v = make_float4(0.f, 0.f, 0.f, 0.f);
            if (node < n_nodes) v = x4[node * (IN_CH / 4) + c4];
            uint2 p;
            p.x = ((unsigned)f2bf(v.y) << 16) | f2bf(v.x);
            p.y = ((unsigned)f2bf(v.w) << 16) | f2bf(v.z);
            *(uint2*)&Xs[row][c4 * 4] = p;
        }
    }
    __syncthreads();

    floatx4 acc[8][2];
#pragma unroll
    for (int mi = 0; mi < 8; ++mi)
#pragma unroll
        for (int ni = 0; ni < 2; ++ni)
            acc[mi][ni] = (floatx4){0.f, 0.f, 0.f, 0.f};

#pragma unroll
    for (int ks = 0; ks < 4; ++ks) {
        const int k0 = ks * 32 + quad * 8;
#pragma unroll
        for (int mi = 0; mi < 8; ++mi) {
            short8 a = *(const short8*)&Xs[mi * 16 + l15][k0];
            acc[mi][0] = __builtin_amdgcn_mfma_f32_16x16x32_bf16(a, bfrag[ks][0], acc[mi][0], 0, 0, 0);
            acc[mi][1] = __builtin_amdgcn_mfma_f32_16x16x32_bf16(a, bfrag[ks][1], acc[mi][1], 0, 0, 0);
        }
    }

    unsigned short* Hout = (w < 2) ? Abf : Bbf;
    const int colb = (w & 1) * 32;
#pragma unroll
    for (int mi = 0; mi < 8; ++mi)
#pragma unroll
        for (int ni = 0; ni < 2; ++ni)
#pragma unroll
            for (int r = 0; r < 4; ++r) {
                long long row = node0 + mi * 16 + quad * 4 + r;
                if (row < n_nodes)
                    Hout[row * OUT_CH + colb + ni * 16 + l15] = f2bf(acc[mi][ni][r]);
            }
}

// ---------------------------------------------------------------------------
// Kernel 3 (NEW structure): edge-parallel over a 64-node target range.
// Block owns nodes [64b, 64b+64). Its in/out edge ranges are CONTIGUOUS
// (targets sorted + CSR rowptrs). Waves process 64-edge packs of the range:
// eighth e of wave w handles 8 CONSECUTIVE edges of pack (w + 4m).
//   - no per-node padding (R1 padded every 8-node group to the max degree:
//     ~3.2M slots for 2M edges); now ~2.05M slots.
//   - per-block (not per-node) rowptr loads; startup chains amortized over
//     the whole block's edge range.
//   - work per block balanced (sum of 64 node degrees, CLT).
// Accumulation: 8 consecutive edges per eighth usually span 1-2 targets ->
// in-register merge by target run, flush runs via ds_add_f32 atomics into a
// padded LDS accumulator (stride 68 words spreads flush banks; same-address
// collisions only at run boundaries / rare high-degree targets).
// Gathers double-buffered (2 packs in flight), edge stream prefetched 2
// packs ahead (proven R1 pipeline skeleton).
// Epilogue: out = acc + ci*(bmi+bsi) + co*(bmo+bso), f32x4 stores.
// C scaling folded per-edge: wj = ew * C[tgt] (exactly distributive for the
// per-target constant; matches reference within tolerance).
// ---------------------------------------------------------------------------
__global__ __launch_bounds__(256)
void prop_kernel(const unsigned short* __restrict__ H,   // A base; B = A + Boff
                 const int* __restrict__ rpIn, const int* __restrict__ rpOut,
                 const int* __restrict__ srcIn, const float* __restrict__ ewIn,
                 const int* __restrict__ tgtIn,
                 const int* __restrict__ srcOut, const float* __restrict__ ewOut,
                 const int* __restrict__ tgtOut,
                 const float* __restrict__ bmi, const float* __restrict__ bmo,
                 const float* __restrict__ bsi, const float* __restrict__ bso,
                 const float* __restrict__ Cin, const float* __restrict__ Cout,
                 float* __restrict__ out, int n_nodes, int neIn, int neOut)
{
    __shared__ float accL[NB * ACC_STRIDE];   // 17408 B
    __shared__ float CinL[NB], CoutL[NB];
    __shared__ float bInL[OUT_CH], bOutL[OUT_CH];

    const int tid  = threadIdx.x;
    const int base = (int)blockIdx.x * NB;
    const int nb   = min(NB, n_nodes - base);

    // ---- stage: zero acc, node C values, combined biases
    for (int i = tid; i < NB * ACC_STRIDE; i += 256) accL[i] = 0.f;
    if (tid < NB) {
        int node = base + min(tid, nb - 1);
        CinL[tid]  = Cin[node];
        CoutL[tid] = Cout[node];
    } else if (tid < NB + OUT_CH) {
        int c = tid - NB;
        bInL[c]  = bmi[c] + bsi[c];
        bOutL[c] = bmo[c] + bso[c];
    }
    __syncthreads();

    const int lane = tid & 63;
    const int wv   = tid >> 6;
    const int e    = lane >> 3;           // eighth within wave
    const int el   = lane & 7;            // lane within eighth
    const int ch8  = el * 8;              // my 8 bf16 channels
    const int eb   = lane & 56;           // eighth base lane

    float* accP = accL + ch8;             // lane channel base into acc rows

    const int Boff = n_nodes * OUT_CH;

    // ---- process one edge set over this block's contiguous edge range
    auto run_set = [&](const int* __restrict__ srcS, const float* __restrict__ ewS,
                       const int* __restrict__ tgtS, int i0, int i1,
                       const float* __restrict__ CL, const unsigned short* __restrict__ Hs)
    {
        const int ein = i1 - i0;
        if (ein <= 0) return;
        const unsigned short* Hq = Hs + ch8;
        const int NPK = (ein + 63) >> 6;              // 64-edge wave-packs

        auto mvalid = [&](int m) { return (wv + 4 * m) < NPK; };   // wave-uniform

        // raw edge load for my pack m, slot el (clamped; w=0 marks pad)
        auto loadE = [&](int m, int& s, float& w, int& t) {
            int g   = (wv + 4 * m) * 64 + e * 8 + el;
            int idx = i0 + min(g, ein - 1);
            s = srcS[idx]; w = ewS[idx]; t = tgtS[idx];
            if (g >= ein) w = 0.f;
        };

        // prep: local target + C-scaled weight, broadcast rows, issue 8 gathers
        auto prep = [&](int s, float w, int t, int& tl, float& wj, uint4 (&u)[8]) {
            tl = t - base;
            wj = w * CL[tl];
#pragma unroll
            for (int k = 0; k < 8; ++k) {
                int sk = __shfl(s, eb + k);
                u[k] = *(const uint4*)(Hq + sk * OUT_CH);
            }
        };

        // merge: walk 8 consecutive edges, in-register sum per target run,
        // flush each run with 8 ds_add_f32 (branch uniform within an eighth)
        auto merge = [&](int tl, float wj, const uint4 (&u)[8]) {
            int cur = __shfl(tl, eb);
            float s0 = 0.f, s1 = 0.f, s2 = 0.f, s3 = 0.f;
            float s4 = 0.f, s5 = 0.f, s6 = 0.f, s7 = 0.f;
#pragma unroll
            for (int k = 0; k < 8; ++k) {
                int   tk = __shfl(tl, eb + k);
                float wk = __shfl(wj, eb + k);
                if (tk != cur) {
                    float* p = accP + cur * ACC_STRIDE;
                    atomicAdd(p + 0, s0); atomicAdd(p + 1, s1);
                    atomicAdd(p + 2, s2); atomicAdd(p + 3, s3);
                    atomicAdd(p + 4, s4); atomicAdd(p + 5, s5);
                    atomicAdd(p + 6, s6); atomicAdd(p + 7, s7);
                    s0 = s1 = s2 = s3 = s4 = s5 = s6 = s7 = 0.f;
                    cur = tk;
                }
                uint4 uk = u[k];
                s0 += wk * bfl(uk.x); s1 += wk * bfh(uk.x);
                s2 += wk * bfl(uk.y); s3 += wk * bfh(uk.y);
                s4 += wk * bfl(uk.z); s5 += wk * bfh(uk.z);
                s6 += wk * bfl(uk.w); s7 += wk * bfh(uk.w);
            }
            float* p = accP + cur * ACC_STRIDE;
            atomicAdd(p + 0, s0); atomicAdd(p + 1, s1);
            atomicAdd(p + 2, s2); atomicAdd(p + 3, s3);
            atomicAdd(p + 4, s4); atomicAdd(p + 5, s5);
            atomicAdd(p + 6, s6); atomicAdd(p + 7, s7);
        };

        if (!mvalid(0)) return;           // this wave has no packs

        int   sA, tA; float wA;
        int   sB, tB; float wB;
        int   tlA, tlB; float wjA, wjB;
        uint4 uA[8], uB[8];

        // ---- prologue: fill both stages
        loadE(0, sA, wA, tA);
        const bool v1 = mvalid(1);
        if (v1) loadE(1, sB, wB, tB);
        prep(sA, wA, tA, tlA, wjA, uA);               // pack m=0 gathers in flight
        if (mvalid(2)) loadE(2, sA, wA, tA);
        if (v1) {
            prep(sB, wB, tB, tlB, wjB, uB);           // pack m=1 gathers in flight
            if (mvalid(3)) loadE(3, sB, wB, tB);
        }

        // ---- steady state: consume m / m+1, prep m+2 / m+3
        for (int m = 0; mvalid(m); m += 2) {
            merge(tlA, wjA, uA);                      // pack m
            if (mvalid(m + 2)) {
                prep(sA, wA, tA, tlA, wjA, uA);       // pack m+2 in flight
                if (mvalid(m + 4)) loadE(m + 4, sA, wA, tA);
            }
            if (mvalid(m + 1)) {
                merge(tlB, wjB, uB);                  // pack m+1
                if (mvalid(m + 3)) {
                    prep(sB, wB, tB, tlB, wjB, uB);   // pack m+3 in flight
                    if (mvalid(m + 5)) loadE(m + 5, sB, wB, tB);
                }
            }
        }
    };

    run_set(srcIn,  ewIn,  tgtIn,  rpIn[base],  rpIn[base + nb],  CinL,  H);
    run_set(srcOut, ewOut, tgtOut, rpOut[base], rpOut[base + nb], CoutL, H + Boff);

    __syncthreads();

    // ---- epilogue: out[node] = acc + ci*(bmi+bsi) + co*(bmo+bso)
    for (int j = tid; j < nb * 16; j += 256) {
        int i = j >> 4;
        int q = (j & 15) * 4;
        float ci = CinL[i], co = CoutL[i];
        const float* ar = accL + i * ACC_STRIDE + q;
        float4 v;
        v.x = ar[0] + ci * bInL[q + 0] + co * bOutL[q + 0];
        v.y = ar[1] + ci * bInL[q + 1] + co * bOutL[q + 1];
        v.z = ar[2] + ci * bInL[q + 2] + co * bOutL[q + 2];
        v.w = ar[3] + ci * bInL[q + 3] + co * bOutL[q + 3];
        *(float4*)(out + (long long)(base + i) * OUT_CH + q) = v;
    }
}

// ---------------------------------------------------------------------------
extern "C" void kernel_launch(void* const* d_in, const int* in_sizes, int n_in,
                              void* d_out, int out_size, void* d_ws, size_t ws_size,
                              hipStream_t stream)
{
    const float* x    = (const float*)d_in[0];
    const float* Wmi  = (const float*)d_in[1];
    const float* Wmo  = (const float*)d_in[2];
    const float* Wsh  = (const float*)d_in[3];
    const float* bmi  = (const float*)d_in[4];
    const float* bmo  = (const float*)d_in[5];
    const float* bsi  = (const float*)d_in[6];
    const float* bso  = (const float*)d_in[7];
    const float* Cin  = (const float*)d_in[8];
    const float* Cout = (const float*)d_in[9];
    const int*   eiIn  = (const int*)d_in[10];
    const float* ewIn  = (const float*)d_in[11];
    const int*   eiOut = (const int*)d_in[12];
    const float* ewOut = (const float*)d_in[13];

    const int n_nodes = in_sizes[0] / IN_CH;   // 100000
    const int neIn  = in_sizes[11];            // 1000000
    const int neOut = in_sizes[13];

    const int* srcIn  = eiIn;                  // edge_index[0]
    const int* tgtIn  = eiIn + neIn;           // edge_index[1] (sorted)
    const int* srcOut = eiOut;
    const int* tgtOut = eiOut + neOut;

    // Workspace layout: Abf|Bbf contiguous (bf16) | rpIn | rpOut | WcT (bf16)
    char* ws = (char*)d_ws;
    size_t NH = (size_t)n_nodes * OUT_CH * sizeof(unsigned short);
    unsigned short* Abf = (unsigned short*)ws;
    unsigned short* Bbf = (unsigned short*)(ws + NH);
    int* rpIn  = (int*)(ws + 2 * NH);
    int* rpOut = rpIn + (n_nodes + 1);
    unsigned short* WcT = (unsigned short*)(rpOut + (n_nodes + 1));

    // 1) rowptrs + combined-weight bf16 pre-pack
    int prep_threads = 2 * (n_nodes + 1) + 2 * OUT_CH * IN_CH;
    prep_kernel<<<(prep_threads + 255) / 256, 256, 0, stream>>>(
        tgtIn, tgtOut, Wmi, Wmo, Wsh, rpIn, rpOut, WcT, n_nodes, neIn, neOut);

    // 2) fused dense transform via MFMA (N=128 GEMM: [A|B] columns)
    int gblocks = (n_nodes + M_TILE - 1) / M_TILE;
    gemm_kernel<<<gblocks, 256, 0, stream>>>(x, WcT, Abf, Bbf, n_nodes);

    // 3) edge-parallel segmented gather-sum into LDS acc + epilogue
    int pblocks = (n_nodes + NB - 1) / NB;     // 64 nodes per block
    prop_kernel<<<pblocks, 256, 0, stream>>>(
        Abf, rpIn, rpOut, srcIn, ewIn, tgtIn, srcOut, ewOut, tgtOut,
        bmi, bmo, bsi, bso, Cin, Cout, (float*)d_out, n_nodes, neIn, neOut);
}